// Round 1
// 322.604 us; speedup vs baseline: 1.0282x; 1.0282x over previous
//
#include <hip/hip_runtime.h>
#include <hip/hip_bf16.h>
#include <math.h>

// B=32, H=64, W=64, C_IN=384, C_HID=128
// conv3x3(pad1)+b1 -> relu -> conv1x1+b2 -> sigmoid, NHWC fp32.
// Implicit GEMM, halo-LDS (double-buffered), tap-sharing, BIG M:
//   per block: 16x16 output pixels (M=256), N=128, K=9*384. Grid 512 = 2/CU.
//   chunk loop (12 x 32ch): one barrier/chunk; halo 18x18 px x 32ch bf16.
// R1 changes vs baseline:
//   * LDS XOR swizzle at 16B granularity (quarter ^= px&3): kills the 8-way
//     bank-conflict class on af ds_read_b128 (was +4 cyc/read, 5.3M cycles).
//     Write side stays conflict-free (same involution, rule #21).
//   * s_setprio(1) around each 18-h MFMA block (T5: waves have staging vs
//     compute role diversity at 2 blocks/CU).
//   * B-frag loads hoisted to top of each ox body (~200cy more L2 lead).
//   * svalid[6] -> bitmask (register budget neutral; 252/256 regs is tight).

typedef __attribute__((ext_vector_type(8))) unsigned short ushort8;
typedef __attribute__((ext_vector_type(8))) __bf16 bf16x8;
typedef __attribute__((ext_vector_type(4))) float floatx4;

#define HPX 324            // 18*18 halo pixels
#define BUFE 10368         // HPX*32 elems per chunk buffer

static __device__ __forceinline__ unsigned short f2bf_rne(float f) {
  union { float f; unsigned int u; } x; x.f = f;
  unsigned int u = x.u;
  return (unsigned short)((u + 0x7fffu + ((u >> 16) & 1u)) >> 16);
}

static __device__ __forceinline__ ushort8 pack8(const float* v) {
  ushort8 r;
#pragma unroll
  for (int i = 0; i < 4; ++i) {
    __hip_bfloat162 p = __float22bfloat162_rn(make_float2(v[2 * i], v[2 * i + 1]));
    union { __hip_bfloat162 b; unsigned int u; } c;
    c.b = p;
    r[2 * i] = (unsigned short)(c.u & 0xffffu);
    r[2 * i + 1] = (unsigned short)(c.u >> 16);
  }
  return r;
}

// W1 (3,3,384,128 HWIO fp32) -> bf16 W1b[kk][n][c], kk=o*12+chunk, n=0..127, c=0..31.
__global__ void prep_w1_kernel(const float* __restrict__ W1,
                               unsigned short* __restrict__ W1b) {
  __shared__ unsigned short tile[32 * 128];
  const int kk = blockIdx.x;            // 0..107
  const int o = kk / 12;
  const int chunk = kk - o * 12;
  const float* src = W1 + (o * 384 + chunk * 32) * 128;  // [c][n], n contiguous
  const int t = threadIdx.x;
#pragma unroll
  for (int i = 0; i < 16; ++i) {
    int idx = t + i * 256;              // idx = c*128+n
    int c = idx >> 7;
    int n = idx & 127;
    tile[n * 32 + c] = f2bf_rne(src[idx]);
  }
  __syncthreads();
  unsigned short* dst = W1b + kk * 4096;
#pragma unroll
  for (int i = 0; i < 16; ++i) {
    int idx = t + i * 256;
    dst[idx] = tile[idx];
  }
}

__global__ __launch_bounds__(256, 2) void conv_fused_kernel(
    const float* __restrict__ x, const unsigned short* __restrict__ W1b,
    const float* __restrict__ b1, const float* __restrict__ W2,
    const float* __restrict__ b2, float* __restrict__ out) {
  __shared__ alignas(16) unsigned short Ah[2 * BUFE];  // 41472 B
  __shared__ float hsum[256 * 4];                      // 4096 B

  const int t = threadIdx.x;
  const int w = t >> 6;        // wave 0..3 -> n block [32w, 32w+32)
  const int lane = t & 63;
  const int g = lane >> 4;     // quad (k-sub)
  const int lr = lane & 15;

  const int img = blockIdx.x >> 4;       // 32 images
  const int tileId = blockIdx.x & 15;    // 4x4 grid of 16x16 tiles
  const int ty0 = (tileId >> 2) << 4;
  const int tx0 = (tileId & 3) << 4;

  // ---- staging plan: 1296 items (halo px 0..323 x sub 0..3), 8 ch each ----
  // item = t + 256*j, j=0..5 (j=5 active only t<16).
  // LDS 16B-unit for (px,sub) is SWIZZLED: unit = px*4 + (sub ^ (px&3)).
  // Since item = px*4+sub, swizzled item = item ^ ((t>>2)&3) (jj*256 = 0 mod 4).
  int smask = 0;
  int soff[6];
#pragma unroll
  for (int j = 0; j < 6; ++j) {
    int item = t + (j << 8);
    int px = item >> 2, sub = item & 3;
    int hy = (px * 57) >> 10;            // px/18 for px<1024
    int hx = px - hy * 18;
    int iy = ty0 + hy - 1, ix = tx0 + hx - 1;
    int v = (item < 1296) && ((unsigned)iy < 64u) && ((unsigned)ix < 64u);
    smask |= (v << j);
    int iyc = v ? iy : 0, ixc = v ? ix : 0;
    soff[j] = ((((img << 6) + iyc) << 6) + ixc) * 384 + sub * 8;
  }
  const int tsw = t ^ ((t >> 2) & 3);    // swizzled write lane index

  // B frag offset (elems): row n = w*32 + lr (+16 for ni=1), k-sub = g*8
  const int boff = ((w * 32 + lr) << 5) + (g << 3);
  // A frag lane offsets (elems), one per P0&3 residue:
  //   px = P0 + lr, quarter read = g ^ (px&3)  (matches write swizzle)
  int lo[4];
#pragma unroll
  for (int q = 0; q < 4; ++q)
    lo[q] = (lr << 5) + ((g ^ ((q + lr) & 3)) << 3);

  floatx4 acc[16][2] = {};  // pixel row = mi, pixel col = g*4+r, ch n = w*32+ni*16+lr

  const float b1v0 = b1[w * 32 + lr];
  const float b1v1 = b1[w * 32 + 16 + lr];
  const float w2v0 = W2[w * 32 + lr];
  const float w2v1 = W2[w * 32 + 16 + lr];

  float sr[3][8];

  // ---- prologue: stage chunk 0 into buf0 (two groups of 3 items) ----
#pragma unroll
  for (int grp = 0; grp < 2; ++grp) {
#pragma unroll
    for (int j = 0; j < 3; ++j) {
      const int jj = grp * 3 + j;
      if ((smask >> jj) & 1) {
        *(float4*)&sr[j][0] = *(const float4*)(x + soff[jj]);
        *(float4*)&sr[j][4] = *(const float4*)(x + soff[jj] + 4);
      } else {
#pragma unroll
        for (int e = 0; e < 8; ++e) sr[j][e] = 0.0f;
      }
    }
#pragma unroll
    for (int j = 0; j < 3; ++j) {
      const int jj = grp * 3 + j;
      if (jj < 5 || t < 16)
        *(ushort8*)&Ah[(tsw + (jj << 8)) << 3] = pack8(sr[j]);
    }
  }
  __syncthreads();

  for (int c = 0; c < 12; ++c) {
    const int rb = (c & 1) * BUFE;        // read buffer (chunk c)
    const int wb = BUFE - rb;             // write buffer (chunk c+1)
    const int choff = (c + 1) << 5;
    const bool pf = (c < 11);

#pragma unroll
    for (int ox = 0; ox < 3; ++ox) {
      // ---- B frags for this ox first (6 x 16B from L2-resident W1b) ----
      bf16x8 bf[3][2];
#pragma unroll
      for (int oy = 0; oy < 3; ++oy) {
        const unsigned short* bp =
            W1b + (((oy * 3 + ox) * 12 + c) << 12) + boff;
        bf[oy][0] = *(const bf16x8*)bp;
        bf[oy][1] = *(const bf16x8*)(bp + 512);
      }

      // ---- staging interleave: write prev group / load next group ----
      if (ox == 0) {
        if (pf) {
#pragma unroll
          for (int j = 0; j < 3; ++j) {
            if ((smask >> j) & 1) {
              *(float4*)&sr[j][0] = *(const float4*)(x + soff[j] + choff);
              *(float4*)&sr[j][4] = *(const float4*)(x + soff[j] + choff + 4);
            } else {
#pragma unroll
              for (int e = 0; e < 8; ++e) sr[j][e] = 0.0f;
            }
          }
        }
      } else if (ox == 1) {
        if (pf) {
#pragma unroll
          for (int j = 0; j < 3; ++j)
            *(ushort8*)&Ah[wb + ((tsw + (j << 8)) << 3)] = pack8(sr[j]);
#pragma unroll
          for (int j = 0; j < 3; ++j) {
            const int jj = 3 + j;
            if ((smask >> jj) & 1) {
              *(float4*)&sr[j][0] = *(const float4*)(x + soff[jj] + choff);
              *(float4*)&sr[j][4] = *(const float4*)(x + soff[jj] + choff + 4);
            } else {
#pragma unroll
              for (int e = 0; e < 8; ++e) sr[j][e] = 0.0f;
            }
          }
        }
      } else {  // ox == 2
        if (pf) {
#pragma unroll
          for (int j = 0; j < 3; ++j) {
            const int jj = 3 + j;
            if (jj < 5 || t < 16)
              *(ushort8*)&Ah[wb + ((tsw + (jj << 8)) << 3)] = pack8(sr[j]);
          }
        }
      }

      // ---- tap-shared MFMAs: A-frag at halo row h feeds oy with mi=h-oy ----
      __builtin_amdgcn_s_setprio(1);
#pragma unroll
      for (int h = 0; h < 18; ++h) {
        const int P0 = h * 18 + ox;      // compile-time after unroll
        const bf16x8 af =
            *(const bf16x8*)&Ah[rb + (P0 << 5) + lo[P0 & 3]];
#pragma unroll
        for (int oy = 0; oy < 3; ++oy) {
          const int mi = h - oy;
          if (mi >= 0 && mi < 16) {
            acc[mi][0] = __builtin_amdgcn_mfma_f32_16x16x32_bf16(
                af, bf[oy][0], acc[mi][0], 0, 0, 0);
            acc[mi][1] = __builtin_amdgcn_mfma_f32_16x16x32_bf16(
                af, bf[oy][1], acc[mi][1], 0, 0, 0);
          }
        }
      }
      __builtin_amdgcn_s_setprio(0);
    }
    __syncthreads();
  }

  // ---- epilogue: bias+relu, conv1x1 reduce over n, sigmoid ----
#pragma unroll
  for (int mi = 0; mi < 16; ++mi) {
#pragma unroll
    for (int r = 0; r < 4; ++r) {
      float h0 = fmaxf(acc[mi][0][r] + b1v0, 0.0f);
      float h1 = fmaxf(acc[mi][1][r] + b1v1, 0.0f);
      float v = h0 * w2v0 + h1 * w2v1;
      v += __shfl_xor(v, 1);
      v += __shfl_xor(v, 2);
      v += __shfl_xor(v, 4);
      v += __shfl_xor(v, 8);
      if (lr == 0) {
        int m = mi * 16 + g * 4 + r;  // pixel row = mi, pixel col = g*4+r
        hsum[m * 4 + w] = v;
      }
    }
  }
  __syncthreads();
  {
    float s = hsum[t * 4 + 0] + hsum[t * 4 + 1] + hsum[t * 4 + 2] +
              hsum[t * 4 + 3] + b2[0];
    float sig = 1.0f / (1.0f + expf(-s));
    int prow = t >> 4, pcol = t & 15;
    out[((((img << 6) + ty0 + prow) << 6) + tx0 + pcol)] = sig;
  }
}

extern "C" void kernel_launch(void* const* d_in, const int* in_sizes, int n_in,
                              void* d_out, int out_size, void* d_ws, size_t ws_size,
                              hipStream_t stream) {
  const float* x  = (const float*)d_in[0];   // (32,64,64,384)
  const float* W1 = (const float*)d_in[1];   // (3,3,384,128)
  const float* b1 = (const float*)d_in[2];   // (128)
  const float* W2 = (const float*)d_in[3];   // (128)
  const float* b2 = (const float*)d_in[4];   // (1)
  float* out = (float*)d_out;                // (32,64,64,1)
  unsigned short* W1b = (unsigned short*)d_ws;  // 108*4096*2 = 884736 B

  prep_w1_kernel<<<108, 256, 0, stream>>>(W1, W1b);
  conv_fused_kernel<<<512, 256, 0, stream>>>(x, W1b, b1, W2, b2, out);
}

// Round 2
// 320.364 us; speedup vs baseline: 1.0354x; 1.0070x over previous
//
#include <hip/hip_runtime.h>
#include <hip/hip_bf16.h>
#include <math.h>

// B=32, H=64, W=64, C_IN=384, C_HID=128
// conv3x3(pad1)+b1 -> relu -> conv1x1+b2 -> sigmoid, NHWC fp32.
// Implicit GEMM, halo-LDS (double-buffered), tap-sharing, BIG M:
//   per block: 16x16 output pixels (M=256), N=128, K=9*384. Grid 512 = 2/CU.
//   chunk loop (12 x 32ch): one barrier/chunk; halo 18x18 px x 32ch bf16.
// R2 changes vs R1:
//   * 8-wave blocks (512 thr), N=16 per wave: acc[16] = 64 AGPR (was 128).
//     Total regs ~125/wave -> __launch_bounds__(512,4) = 4 waves/SIMD
//     (was 2). Doubles latency-hiding wave pool; same MFMA work per SIMD.
//   * Swizzle REMOVED: R1 proved SQ_LDS_BANK_CONFLICT is structural to
//     full-wave ds_read_b128 (exactly 4/read, invariant under swizzle).
//     af reads are now base+immediate (zero per-read VALU).
//   * Staging split across 512 threads (<=3 items/thread, was 6).
//   * Keep: s_setprio around MFMA blocks, B-frag hoist (R1 winners).

typedef __attribute__((ext_vector_type(8))) unsigned short ushort8;
typedef __attribute__((ext_vector_type(8))) __bf16 bf16x8;
typedef __attribute__((ext_vector_type(4))) float floatx4;

#define HPX 324            // 18*18 halo pixels
#define BUFE 10368         // HPX*32 elems per chunk buffer

static __device__ __forceinline__ unsigned short f2bf_rne(float f) {
  union { float f; unsigned int u; } x; x.f = f;
  unsigned int u = x.u;
  return (unsigned short)((u + 0x7fffu + ((u >> 16) & 1u)) >> 16);
}

static __device__ __forceinline__ ushort8 pack8(const float* v) {
  ushort8 r;
#pragma unroll
  for (int i = 0; i < 4; ++i) {
    __hip_bfloat162 p = __float22bfloat162_rn(make_float2(v[2 * i], v[2 * i + 1]));
    union { __hip_bfloat162 b; unsigned int u; } c;
    c.b = p;
    r[2 * i] = (unsigned short)(c.u & 0xffffu);
    r[2 * i + 1] = (unsigned short)(c.u >> 16);
  }
  return r;
}

// W1 (3,3,384,128 HWIO fp32) -> bf16 W1b[kk][n][c], kk=o*12+chunk, n=0..127, c=0..31.
__global__ void prep_w1_kernel(const float* __restrict__ W1,
                               unsigned short* __restrict__ W1b) {
  __shared__ unsigned short tile[32 * 128];
  const int kk = blockIdx.x;            // 0..107
  const int o = kk / 12;
  const int chunk = kk - o * 12;
  const float* src = W1 + (o * 384 + chunk * 32) * 128;  // [c][n], n contiguous
  const int t = threadIdx.x;
#pragma unroll
  for (int i = 0; i < 16; ++i) {
    int idx = t + i * 256;              // idx = c*128+n
    int c = idx >> 7;
    int n = idx & 127;
    tile[n * 32 + c] = f2bf_rne(src[idx]);
  }
  __syncthreads();
  unsigned short* dst = W1b + kk * 4096;
#pragma unroll
  for (int i = 0; i < 16; ++i) {
    int idx = t + i * 256;
    dst[idx] = tile[idx];
  }
}

__global__ __launch_bounds__(512, 4) void conv_fused_kernel(
    const float* __restrict__ x, const unsigned short* __restrict__ W1b,
    const float* __restrict__ b1, const float* __restrict__ W2,
    const float* __restrict__ b2, float* __restrict__ out) {
  __shared__ alignas(16) unsigned short Ah[2 * BUFE];  // 41472 B
  __shared__ float hsum[256 * 8];                      // 8192 B

  const int t = threadIdx.x;
  const int w = t >> 6;        // wave 0..7 -> n block [16w, 16w+16)
  const int lane = t & 63;
  const int g = lane >> 4;     // quad (k-sub)
  const int lr = lane & 15;

  const int img = blockIdx.x >> 4;       // 32 images
  const int tileId = blockIdx.x & 15;    // 4x4 grid of 16x16 tiles
  const int ty0 = (tileId >> 2) << 4;
  const int tx0 = (tileId & 3) << 4;

  // ---- staging plan: 1296 items (halo px 0..323 x sub 0..3), 8 ch each ----
  // item = t + 512*j, j=0..2 (j=2 active only t<272). LDS unit = item
  // (flat [px][32ch] layout -> consecutive lanes write consecutive 16B).
  int smask = 0;
  int soff[3];
#pragma unroll
  for (int j = 0; j < 3; ++j) {
    int item = t + (j << 9);
    int px = item >> 2, sub = item & 3;
    int hy = (px * 57) >> 10;            // px/18 for px<1024
    int hx = px - hy * 18;
    int iy = ty0 + hy - 1, ix = tx0 + hx - 1;
    int v = (item < 1296) && ((unsigned)iy < 64u) && ((unsigned)ix < 64u);
    smask |= (v << j);
    int iyc = v ? iy : 0, ixc = v ? ix : 0;
    soff[j] = ((((img << 6) + iyc) << 6) + ixc) * 384 + sub * 8;
  }

  // B frag offset (elems): row n = w*16 + lr, k-sub = g*8
  const int boff = ((w * 16 + lr) << 5) + (g << 3);
  // A frag lane part (elems): halo px col lr (+ox), ch quarter g
  const int aoffl = (lr << 5) + (g << 3);

  floatx4 acc[16] = {};  // pixel row = mi, pixel col = g*4+r, ch n = w*16+lr

  const float b1v = b1[w * 16 + lr];
  const float w2v = W2[w * 16 + lr];

  float sg1[8];      // group 1 = item j=0
  float sr[2][8];    // group 2 = items j=1,2

  // ---- prologue: stage chunk 0 into buf0 ----
  {
    if (smask & 1) {
      *(float4*)&sg1[0] = *(const float4*)(x + soff[0]);
      *(float4*)&sg1[4] = *(const float4*)(x + soff[0] + 4);
    } else {
#pragma unroll
      for (int e = 0; e < 8; ++e) sg1[e] = 0.0f;
    }
#pragma unroll
    for (int j = 0; j < 2; ++j) {
      const int jj = 1 + j;
      if ((smask >> jj) & 1) {
        *(float4*)&sr[j][0] = *(const float4*)(x + soff[jj]);
        *(float4*)&sr[j][4] = *(const float4*)(x + soff[jj] + 4);
      } else {
#pragma unroll
        for (int e = 0; e < 8; ++e) sr[j][e] = 0.0f;
      }
    }
    *(ushort8*)&Ah[t << 3] = pack8(sg1);
    *(ushort8*)&Ah[(t + 512) << 3] = pack8(sr[0]);
    if (t < 272) *(ushort8*)&Ah[(t + 1024) << 3] = pack8(sr[1]);
  }
  __syncthreads();

  for (int c = 0; c < 12; ++c) {
    const int rb = (c & 1) * BUFE;        // read buffer (chunk c)
    const int wb = BUFE - rb;             // write buffer (chunk c+1)
    const int choff = (c + 1) << 5;
    const bool pf = (c < 11);

#pragma unroll
    for (int ox = 0; ox < 3; ++ox) {
      // ---- B frags for this ox first (3 x 16B from L2-resident W1b) ----
      bf16x8 bf[3];
#pragma unroll
      for (int oy = 0; oy < 3; ++oy) {
        const unsigned short* bp =
            W1b + (((oy * 3 + ox) * 12 + c) << 12) + boff;
        bf[oy] = *(const bf16x8*)bp;
      }

      // ---- staging interleave: write prev group / load next group ----
      if (ox == 0) {
        if (pf) {
          if (smask & 1) {
            *(float4*)&sg1[0] = *(const float4*)(x + soff[0] + choff);
            *(float4*)&sg1[4] = *(const float4*)(x + soff[0] + choff + 4);
          } else {
#pragma unroll
            for (int e = 0; e < 8; ++e) sg1[e] = 0.0f;
          }
        }
      } else if (ox == 1) {
        if (pf) {
          *(ushort8*)&Ah[wb + (t << 3)] = pack8(sg1);
#pragma unroll
          for (int j = 0; j < 2; ++j) {
            const int jj = 1 + j;
            if ((smask >> jj) & 1) {
              *(float4*)&sr[j][0] = *(const float4*)(x + soff[jj] + choff);
              *(float4*)&sr[j][4] = *(const float4*)(x + soff[jj] + choff + 4);
            } else {
#pragma unroll
              for (int e = 0; e < 8; ++e) sr[j][e] = 0.0f;
            }
          }
        }
      } else {  // ox == 2
        if (pf) {
          *(ushort8*)&Ah[wb + ((t + 512) << 3)] = pack8(sr[0]);
          if (t < 272) *(ushort8*)&Ah[wb + ((t + 1024) << 3)] = pack8(sr[1]);
        }
      }

      // ---- tap-shared MFMAs: A-frag at halo row h feeds oy with mi=h-oy ----
      __builtin_amdgcn_s_setprio(1);
#pragma unroll
      for (int h = 0; h < 18; ++h) {
        const bf16x8 af =
            *(const bf16x8*)&Ah[rb + ((h * 18 + ox) << 5) + aoffl];
#pragma unroll
        for (int oy = 0; oy < 3; ++oy) {
          const int mi = h - oy;
          if (mi >= 0 && mi < 16) {
            acc[mi] = __builtin_amdgcn_mfma_f32_16x16x32_bf16(
                af, bf[oy], acc[mi], 0, 0, 0);
          }
        }
      }
      __builtin_amdgcn_s_setprio(0);
    }
    __syncthreads();
  }

  // ---- epilogue: bias+relu, conv1x1 reduce over n, sigmoid ----
#pragma unroll
  for (int mi = 0; mi < 16; ++mi) {
#pragma unroll
    for (int r = 0; r < 4; ++r) {
      float h0 = fmaxf(acc[mi][r] + b1v, 0.0f);
      float v = h0 * w2v;
      v += __shfl_xor(v, 1);
      v += __shfl_xor(v, 2);
      v += __shfl_xor(v, 4);
      v += __shfl_xor(v, 8);
      if (lr == 0) {
        int m = mi * 16 + g * 4 + r;  // pixel row = mi, pixel col = g*4+r
        hsum[m * 8 + w] = v;
      }
    }
  }
  __syncthreads();
  if (t < 256) {
    float4 p0 = *(const float4*)&hsum[t * 8];
    float4 p1 = *(const float4*)&hsum[t * 8 + 4];
    float s = p0.x + p0.y + p0.z + p0.w + p1.x + p1.y + p1.z + p1.w + b2[0];
    float sig = 1.0f / (1.0f + expf(-s));
    int prow = t >> 4, pcol = t & 15;
    out[((((img << 6) + ty0 + prow) << 6) + tx0 + pcol)] = sig;
  }
}

extern "C" void kernel_launch(void* const* d_in, const int* in_sizes, int n_in,
                              void* d_out, int out_size, void* d_ws, size_t ws_size,
                              hipStream_t stream) {
  const float* x  = (const float*)d_in[0];   // (32,64,64,384)
  const float* W1 = (const float*)d_in[1];   // (3,3,384,128)
  const float* b1 = (const float*)d_in[2];   // (128)
  const float* W2 = (const float*)d_in[3];   // (128)
  const float* b2 = (const float*)d_in[4];   // (1)
  float* out = (float*)d_out;                // (32,64,64,1)
  unsigned short* W1b = (unsigned short*)d_ws;  // 108*4096*2 = 884736 B

  prep_w1_kernel<<<108, 256, 0, stream>>>(W1, W1b);
  conv_fused_kernel<<<512, 512, 0, stream>>>(x, W1b, b1, W2, b2, out);
}